// Round 7
// baseline (147.500 us; speedup 1.0000x reference)
//
#include <hip/hip_runtime.h>
#include <float.h>

#define Bb 2
#define Ll 256
#define Ss 384
#define Hh 768
#define Tc 16
#define Dc 50
#define WD 100
#define CV 128
#define NG 200     // 4*Dc gates
#define OUTC 968   // H + WD + 2*Dc
#define LT 8       // l rows per word block

// ws layout (floats): [0, 51200) xproj table [2][128][200], bias folded in

__device__ inline float tanh_fast(float x) {
    float e = __expf(2.f * x);
    return 1.f - 2.f / (e + 1.f);
}
__device__ inline float sigmoid_fast(float x) {
    return 1.f / (1.f + __expf(-x));
}

// ================= kernel 1: xproj table only =================
// grid 64: idx = dir*32 + cid-chunk(4)

__global__ __launch_bounds__(256) void kernel1(
        const float* __restrict__ char_table,
        const float* __restrict__ Wih_f, const float* __restrict__ bih_f, const float* __restrict__ bhh_f,
        const float* __restrict__ Wih_b, const float* __restrict__ bih_b, const float* __restrict__ bhh_b,
        float* __restrict__ xpt) {
    int blk = blockIdx.x, tid = threadIdx.x;
    int dir = blk >> 5, c0 = (blk & 31) * 4;
    const float* Wih = dir ? Wih_b : Wih_f;
    const float* bih = dir ? bih_b : bih_f;
    const float* bhh = dir ? bhh_b : bhh_f;
    __shared__ float ct[4][Dc];
    if (tid < 4 * Dc) ((float*)ct)[tid] = char_table[c0 * Dc + tid];
    __syncthreads();
    if (tid < NG) {
        float w[Dc];
        #pragma unroll
        for (int j = 0; j < Dc; j++) w[j] = Wih[tid * Dc + j];
        float bias = bih[tid] + bhh[tid];
        #pragma unroll
        for (int cid = 0; cid < 4; cid++) {
            float a = bias;
            #pragma unroll
            for (int j = 0; j < Dc; j++) a += w[j] * ct[cid][j];
            xpt[(dir * CV + c0 + cid) * NG + tid] = a;   // coalesced
        }
    }
}

// ================= kernel 2: LSTM | word_reps | embed =================
// grid 1472: [0,1024) lstm (n=blk>>1, dir=blk&1), [1024,1408) word, [1408,1472) embed
// word block = (b, l-tile of 8, h-chunk of 128); wave owns 96 s

__global__ __launch_bounds__(256) void kernel2(
        const int* __restrict__ char_ids, const int* __restrict__ char_count,
        const float* __restrict__ Whh_f, const float* __restrict__ Whh_b,
        const float* __restrict__ xpt,
        const float* __restrict__ bert, const int* __restrict__ p2w,
        const int* __restrict__ word_ids, const float* __restrict__ word_table,
        float* __restrict__ out) {
    __shared__ __align__(16) char smem[16384];
    int blk = blockIdx.x, tid = threadIdx.x;

    if (blk < 1024) {
        // ---------------- char bi-LSTM ----------------
        float (*xg)[NG] = (float (*)[NG])smem;            // 16*200*4 = 12800
        float* gs  = (float*)(smem + 12800);              // 800
        float* hs  = (float*)(smem + 13600);              // 208 (52 floats)
        int*   scid = (int*)(smem + 13808);               // 64

        int n = blk >> 1, dir = blk & 1;
        const float* Whh = dir ? Whh_b : Whh_f;

        int len = char_count[n];
        if (len < 1) len = 1;
        if (tid < Tc) {
            int t = tid;
            int st = dir ? (t < len ? len - 1 - t : t) : t;   // bwd: reverse valid prefix
            scid[t] = char_ids[n * Tc + st];
        }
        if (tid < 52) hs[tid] = 0.f;
        __syncthreads();

        // stage xproj rows as float4 (row stride 200 floats = 800B, 16B aligned)
        for (int e = tid; e < Tc * (NG / 4); e += 256) {
            int t = e / 50, q = e - t * 50;
            ((float4*)xg[t])[q] = ((const float4*)&xpt[(dir * CV + scid[t]) * NG])[q];
        }
        float w[52];
        if (tid < NG) {
            #pragma unroll
            for (int j = 0; j < Dc; j++) w[j] = Whh[tid * Dc + j];
            w[50] = 0.f; w[51] = 0.f;
        }
        __syncthreads();

        float c = 0.f, maxv = -FLT_MAX;
        for (int t = 0; t < Tc; t++) {
            if (tid < NG) {
                float g = xg[t][tid];
                #pragma unroll
                for (int j = 0; j < 52; j += 4) {
                    float4 hv = *(const float4*)&hs[j];   // broadcast reads
                    g += hv.x * w[j] + hv.y * w[j+1] + hv.z * w[j+2] + hv.w * w[j+3];
                }
                gs[tid] = g;
            }
            __syncthreads();
            if (tid < Dc) {
                float si = sigmoid_fast(gs[tid]);
                float sf = sigmoid_fast(gs[tid + 50]);
                float tg = tanh_fast(gs[tid + 100]);
                float so = sigmoid_fast(gs[tid + 150]);
                c = sf * c + si * tg;
                float h = so * tanh_fast(c);
                hs[tid] = h;
                if (t < len) maxv = fmaxf(maxv, h);       // ragged max
            }
            __syncthreads();
        }
        if (tid < Dc)
            out[(size_t)n * OUTC + (Hh + WD) + dir * Dc + tid] = maxv;
    } else if (blk < 1408) {
        // ---------------- word_reps masked max, direct write ----------------
        float (*sacc)[LT][128] = (float (*)[LT][128])smem;  // 4*8*128*4 = 16384

        int idx = blk - 1024;          // 0..383
        int hc  = idx % 6;             // h-chunk of 128
        int lt  = (idx / 6) & 31;      // l-tile of 8
        int b   = idx / 192;
        int l0  = lt * LT;
        int w    = tid >> 6;           // wave -> s range [w*96, w*96+96)
        int lane = tid & 63;
        int s0 = w * 96;

        // 96-bit row masks via 2 ballots -> 3 SGPRs per row
        const int* pm = p2w + ((size_t)(b * Ll + l0)) * Ss + s0;
        unsigned m0[LT], m1[LT], m2[LT];
        #pragma unroll
        for (int r = 0; r < LT; r++) {
            unsigned long long b0 = __ballot(pm[r * Ss + lane] != 0);
            unsigned long long b1 = __ballot(lane < 32 ? (pm[r * Ss + 64 + lane] != 0) : false);
            m0[r] = __builtin_amdgcn_readfirstlane((unsigned)b0);
            m1[r] = __builtin_amdgcn_readfirstlane((unsigned)(b0 >> 32));
            m2[r] = __builtin_amdgcn_readfirstlane((unsigned)b1);
        }

        const float2* bb2 = (const float2*)(bert + (size_t)b * Ss * Hh) + hc * 64 + lane;
        float2 acc[LT];
        #pragma unroll
        for (int r = 0; r < LT; r++) { acc[r].x = -FLT_MAX; acc[r].y = -FLT_MAX; }

        for (int jo = 0; jo < 96; jo += 8) {       // groups of 8 loads in flight
            float2 v[8];
            #pragma unroll
            for (int k = 0; k < 8; k++) v[k] = bb2[(size_t)(s0 + jo + k) * 384];
            #pragma unroll
            for (int k = 0; k < 8; k++) {
                int j = jo + k;
                #pragma unroll
                for (int r = 0; r < LT; r++) {
                    unsigned bit = (j < 32 ? m0[r] >> j
                                 : j < 64 ? m1[r] >> (j - 32)
                                          : m2[r] >> (j - 64)) & 1u;
                    if (bit) {                     // wave-uniform scalar branch
                        acc[r].x = fmaxf(acc[r].x, v[k].x);
                        acc[r].y = fmaxf(acc[r].y, v[k].y);
                    }
                }
            }
        }
        #pragma unroll
        for (int r = 0; r < LT; r++)
            *(float2*)&sacc[w][r][lane * 2] = acc[r];
        __syncthreads();

        for (int e = tid; e < LT * 128; e += 256) {
            int r = e >> 7, cx = e & 127;
            float m = fmaxf(fmaxf(sacc[0][r][cx], sacc[1][r][cx]),
                            fmaxf(sacc[2][r][cx], sacc[3][r][cx]));
            if (m == -FLT_MAX) {
                // fully-masked row: reference fills with global min of bert.
                // Statistically unreachable (needs 384 zero mask bits); correct slow path.
                float mv = FLT_MAX;
                #pragma unroll 1
                for (int i = 0; i < Bb * Ss * Hh; i++) mv = fminf(mv, bert[i]);
                m = mv;
            }
            out[((size_t)(b * Ll + l0 + r)) * OUTC + hc * 128 + cx] = m;
        }
    } else {
        // ---------------- word-embedding gather ----------------
        for (int i = (blk - 1408) * 256 + tid; i < Bb * Ll * WD; i += 64 * 256) {
            int bl = i / WD, d = i - bl * WD;
            out[(size_t)bl * OUTC + Hh + d] = word_table[(size_t)word_ids[bl] * WD + d];
        }
    }
}

extern "C" void kernel_launch(void* const* d_in, const int* in_sizes, int n_in,
                              void* d_out, int out_size, void* d_ws, size_t ws_size,
                              hipStream_t stream) {
    const float* bert       = (const float*)d_in[0];
    const int*   p2w        = (const int*)d_in[1];
    const int*   word_ids   = (const int*)d_in[2];
    const int*   char_count = (const int*)d_in[3];
    const int*   char_ids   = (const int*)d_in[4];
    // d_in[5] token_masks_char: consistent with char_count, unused
    const float* word_table = (const float*)d_in[6];
    const float* char_table = (const float*)d_in[7];
    const float* Wih_f = (const float*)d_in[8];
    const float* Whh_f = (const float*)d_in[9];
    const float* bih_f = (const float*)d_in[10];
    const float* bhh_f = (const float*)d_in[11];
    const float* Wih_b = (const float*)d_in[12];
    const float* Whh_b = (const float*)d_in[13];
    const float* bih_b = (const float*)d_in[14];
    const float* bhh_b = (const float*)d_in[15];
    float* out = (float*)d_out;

    float* xpt = (float*)d_ws;           // 2*128*200 floats

    kernel1<<<64, 256, 0, stream>>>(
        char_table, Wih_f, bih_f, bhh_f, Wih_b, bih_b, bhh_b, xpt);
    kernel2<<<1472, 256, 0, stream>>>(
        char_ids, char_count, Whh_f, Whh_b, xpt, bert, p2w,
        word_ids, word_table, out);
}

// Round 8
// 127.948 us; speedup vs baseline: 1.1528x; 1.1528x over previous
//
#include <hip/hip_runtime.h>
#include <float.h>

#define Bb 2
#define Ll 256
#define Ss 384
#define Hh 768
#define Tc 16
#define Dc 50
#define WD 100
#define CV 128
#define NG 200     // 4*Dc gates
#define OUTC 968   // H + WD + 2*Dc

// ws layout (floats):
//   [0, 128)    minv partials
//   [128, ...)  xproj table [2][128][200], bias folded in

__device__ inline float tanh_fast(float x) {
    float e = __expf(2.f * x);
    return 1.f - 2.f / (e + 1.f);
}
__device__ inline float sigmoid_fast(float x) {
    return 1.f / (1.f + __expf(-x));
}

// ================= kernel 1: min partials | xproj | embed =================
// grid 256: [0,128) min, [128,192) xproj (dir*32 + cid-chunk of 4), [192,256) embed

__global__ __launch_bounds__(256) void prep_kernel(
        const float* __restrict__ bert, const float* __restrict__ char_table,
        const float* __restrict__ Wih_f, const float* __restrict__ bih_f, const float* __restrict__ bhh_f,
        const float* __restrict__ Wih_b, const float* __restrict__ bih_b, const float* __restrict__ bhh_b,
        const int* __restrict__ word_ids, const float* __restrict__ word_table,
        float* __restrict__ minp, float* __restrict__ xpt, float* __restrict__ out) {
    int blk = blockIdx.x, tid = threadIdx.x;
    if (blk < 128) {
        const int n4 = (Bb * Ss * Hh) / 4;       // 147456 float4
        const float4* b4 = (const float4*)bert;
        float m = FLT_MAX;
        for (int i = blk * 256 + tid; i < n4; i += 128 * 256) {
            float4 v = b4[i];
            m = fminf(m, fminf(fminf(v.x, v.y), fminf(v.z, v.w)));
        }
        #pragma unroll
        for (int off = 32; off; off >>= 1) m = fminf(m, __shfl_down(m, off, 64));
        __shared__ float red[4];
        if ((tid & 63) == 0) red[tid >> 6] = m;
        __syncthreads();
        if (tid == 0) minp[blk] = fminf(fminf(red[0], red[1]), fminf(red[2], red[3]));
    } else if (blk < 192) {
        int idx = blk - 128;            // dir*32 + cid-chunk
        int dir = idx >> 5, c0 = (idx & 31) * 4;
        const float* Wih = dir ? Wih_b : Wih_f;
        const float* bih = dir ? bih_b : bih_f;
        const float* bhh = dir ? bhh_b : bhh_f;
        __shared__ float ct[4][Dc];
        if (tid < 4 * Dc) ((float*)ct)[tid] = char_table[c0 * Dc + tid];
        __syncthreads();
        if (tid < NG) {
            float w[Dc];
            #pragma unroll
            for (int j = 0; j < Dc; j++) w[j] = Wih[tid * Dc + j];
            float bias = bih[tid] + bhh[tid];
            #pragma unroll
            for (int cid = 0; cid < 4; cid++) {
                float a = bias;
                #pragma unroll
                for (int j = 0; j < Dc; j++) a += w[j] * ct[cid][j];
                xpt[(dir * CV + c0 + cid) * NG + tid] = a;   // coalesced
            }
        }
    } else {
        for (int i = (blk - 192) * 256 + tid; i < Bb * Ll * WD; i += 64 * 256) {
            int bl = i / WD, d = i - bl * WD;
            out[(size_t)bl * OUTC + Hh + d] = word_table[(size_t)word_ids[bl] * WD + d];
        }
    }
}

// ================= kernel 2: word_reps masked max =================
// grid 192 = 3 hc(256 floats) * 32 l-tiles(8) * 2 b; 512 threads: wave w owns 48 s

__global__ __launch_bounds__(512) void word_kernel(
        const float* __restrict__ bert, const int* __restrict__ p2w,
        const float* __restrict__ minp, float* __restrict__ out) {
    __shared__ float sacc[8][8][256];    // 64 KB
    __shared__ float sminv;
    int tid = threadIdx.x;
    int wv = tid >> 6, lane = tid & 63;

    if (tid < 64) {
        float m = fminf(minp[tid], minp[tid + 64]);
        #pragma unroll
        for (int off = 32; off; off >>= 1) m = fminf(m, __shfl_down(m, off, 64));
        if (tid == 0) sminv = m;
    }

    int idx = blockIdx.x;
    int hc = idx % 3;              // h-chunk of 256 floats
    int lt = (idx / 3) & 31;       // l-tile of 8
    int b  = idx / 96;
    int l0 = lt * 8;
    int s0 = wv * 48;

    // 48-bit row masks via ballot -> 2 SGPRs per row
    const int* pm = p2w + ((size_t)(b * Ll + l0)) * Ss + s0;
    unsigned mlo[8], mhi[8];
    #pragma unroll
    for (int r = 0; r < 8; r++) {
        unsigned long long bal = __ballot(lane < 48 ? (pm[r * Ss + lane] != 0) : false);
        mlo[r] = __builtin_amdgcn_readfirstlane((unsigned)bal);
        mhi[r] = __builtin_amdgcn_readfirstlane((unsigned)(bal >> 32));
    }

    const float4* bb4 = (const float4*)(bert + (size_t)b * Ss * Hh) + hc * 64 + lane;
    float4 acc[8];
    #pragma unroll
    for (int r = 0; r < 8; r++) { acc[r].x = acc[r].y = acc[r].z = acc[r].w = -FLT_MAX; }

    for (int jo = 0; jo < 48; jo += 8) {        // 8 dwordx4 loads in flight
        float4 v[8];
        #pragma unroll
        for (int k = 0; k < 8; k++) v[k] = bb4[(size_t)(s0 + jo + k) * 192];
        #pragma unroll
        for (int k = 0; k < 8; k++) {
            int j = jo + k;
            #pragma unroll
            for (int r = 0; r < 8; r++) {
                unsigned bit = (j < 32 ? mlo[r] >> j : mhi[r] >> (j - 32)) & 1u;
                if (bit) {                       // wave-uniform scalar branch
                    acc[r].x = fmaxf(acc[r].x, v[k].x);
                    acc[r].y = fmaxf(acc[r].y, v[k].y);
                    acc[r].z = fmaxf(acc[r].z, v[k].z);
                    acc[r].w = fmaxf(acc[r].w, v[k].w);
                }
            }
        }
    }
    #pragma unroll
    for (int r = 0; r < 8; r++)
        *(float4*)&sacc[wv][r][lane * 4] = acc[r];
    __syncthreads();

    float mv = sminv;
    #pragma unroll
    for (int e = tid; e < 8 * 256; e += 512) {
        int r = e >> 8, cx = e & 255;
        float m = sacc[0][r][cx];
        #pragma unroll
        for (int k = 1; k < 8; k++) m = fmaxf(m, sacc[k][r][cx]);
        if (m == -FLT_MAX) m = mv;               // fully-masked row -> global min fill
        out[((size_t)(b * Ll + l0 + r)) * OUTC + hc * 256 + cx] = m;
    }
}

// ================= kernel 3: char bi-LSTM, one wave per (chain, dir) =================
// grid 1024 x 64 threads; lane j<50 owns gates {j, 50+j, 100+j, 150+j}, Whh in registers

__global__ __launch_bounds__(64, 1) void lstm_kernel(
        const int* __restrict__ char_ids, const int* __restrict__ char_count,
        const float* __restrict__ Whh_f, const float* __restrict__ Whh_b,
        const float* __restrict__ xpt, float* __restrict__ out) {
    int blk = blockIdx.x;
    int n = blk >> 1, dir = blk & 1;
    int lane = threadIdx.x;
    const float* Whh = dir ? Whh_b : Whh_f;
    __shared__ __align__(16) float hs[52];

    int len = char_count[n];
    if (len < 1) len = 1;

    // lane t<16 holds scid[t], reversal folded for backward direction
    int cidv = 0;
    if (lane < Tc) {
        int st = dir ? (lane < len ? len - 1 - lane : lane) : lane;
        cidv = char_ids[n * Tc + st];
    }

    // recurrent weights into registers: w[q][0..49], zero-padded to 52
    float w[4][52];
    if (lane < Dc) {
        #pragma unroll
        for (int q = 0; q < 4; q++) {
            const float2* wr = (const float2*)(Whh + (q * Dc + lane) * Dc); // 200B-aligned
            #pragma unroll
            for (int m = 0; m < 25; m++) {
                float2 t = wr[m];
                w[q][2 * m] = t.x; w[q][2 * m + 1] = t.y;
            }
        }
    }
    #pragma unroll
    for (int q = 0; q < 4; q++) { w[q][50] = 0.f; w[q][51] = 0.f; }

    if (lane < 52) hs[lane] = 0.f;
    __syncthreads();

    // prefetch xproj row for t=0
    int cid0 = __shfl(cidv, 0);
    const float* xr = xpt + (size_t)(dir * CV + cid0) * NG;
    float xp[4];
    #pragma unroll
    for (int q = 0; q < 4; q++) xp[q] = (lane < Dc) ? xr[q * Dc + lane] : 0.f;

    float c = 0.f, h = 0.f, maxv = -FLT_MAX;
    for (int t = 0; t < Tc; t++) {
        // prefetch next step's xproj (overlaps the gemv)
        int tn = (t + 1 < Tc) ? t + 1 : t;
        int cidn = __shfl(cidv, tn);
        const float* xrn = xpt + (size_t)(dir * CV + cidn) * NG;
        float xpn[4];
        #pragma unroll
        for (int q = 0; q < 4; q++) xpn[q] = (lane < Dc) ? xrn[q * Dc + lane] : 0.f;

        // gates: g[q] = xp[q] + Whh[q*50+lane,:] . h   (h broadcast from LDS)
        float g0 = xp[0], g1 = xp[1], g2 = xp[2], g3 = xp[3];
        #pragma unroll
        for (int m = 0; m < 13; m++) {
            float4 hv = *(const float4*)&hs[4 * m];
            g0 += hv.x * w[0][4*m] + hv.y * w[0][4*m+1] + hv.z * w[0][4*m+2] + hv.w * w[0][4*m+3];
            g1 += hv.x * w[1][4*m] + hv.y * w[1][4*m+1] + hv.z * w[1][4*m+2] + hv.w * w[1][4*m+3];
            g2 += hv.x * w[2][4*m] + hv.y * w[2][4*m+1] + hv.z * w[2][4*m+2] + hv.w * w[2][4*m+3];
            g3 += hv.x * w[3][4*m] + hv.y * w[3][4*m+1] + hv.z * w[3][4*m+2] + hv.w * w[3][4*m+3];
        }
        if (lane < Dc) {
            float si = sigmoid_fast(g0);
            float sf = sigmoid_fast(g1);
            float tg = tanh_fast(g2);
            float so = sigmoid_fast(g3);
            c = sf * c + si * tg;
            h = so * tanh_fast(c);
            if (t < len) maxv = fmaxf(maxv, h);   // ragged max (scan order == valid region)
        }
        __syncthreads();                          // reads of old hs done (1 wave, cheap)
        if (lane < Dc) hs[lane] = h;
        __syncthreads();                          // write visible before next gemv
        #pragma unroll
        for (int q = 0; q < 4; q++) xp[q] = xpn[q];
    }
    if (lane < Dc)
        out[(size_t)n * OUTC + (Hh + WD) + dir * Dc + lane] = maxv;
}

extern "C" void kernel_launch(void* const* d_in, const int* in_sizes, int n_in,
                              void* d_out, int out_size, void* d_ws, size_t ws_size,
                              hipStream_t stream) {
    const float* bert       = (const float*)d_in[0];
    const int*   p2w        = (const int*)d_in[1];
    const int*   word_ids   = (const int*)d_in[2];
    const int*   char_count = (const int*)d_in[3];
    const int*   char_ids   = (const int*)d_in[4];
    // d_in[5] token_masks_char: consistent with char_count, unused
    const float* word_table = (const float*)d_in[6];
    const float* char_table = (const float*)d_in[7];
    const float* Wih_f = (const float*)d_in[8];
    const float* Whh_f = (const float*)d_in[9];
    const float* bih_f = (const float*)d_in[10];
    const float* bhh_f = (const float*)d_in[11];
    const float* Wih_b = (const float*)d_in[12];
    const float* Whh_b = (const float*)d_in[13];
    const float* bih_b = (const float*)d_in[14];
    const float* bhh_b = (const float*)d_in[15];
    float* out = (float*)d_out;

    float* minp = (float*)d_ws;          // 128 floats
    float* xpt  = minp + 128;            // 2*128*200 floats

    prep_kernel<<<256, 256, 0, stream>>>(
        bert, char_table, Wih_f, bih_f, bhh_f, Wih_b, bih_b, bhh_b,
        word_ids, word_table, minp, xpt, out);
    word_kernel<<<192, 512, 0, stream>>>(bert, p2w, minp, out);
    lstm_kernel<<<1024, 64, 0, stream>>>(
        char_ids, char_count, Whh_f, Whh_b, xpt, out);
}